// Round 11
// baseline (690.219 us; speedup 1.0000x reference)
//
#include <hip/hip_runtime.h>
#include <hip/hip_bf16.h>

namespace {

constexpr int T_ = 96;
constexpr int H_ = 128;

typedef short s8v __attribute__((ext_vector_type(8)));   // 8 bf16 (4 VGPR)
typedef float f4v __attribute__((ext_vector_type(4)));   // MFMA accumulator

__device__ __forceinline__ float rcp_(float x) { return __builtin_amdgcn_rcpf(x); }
__device__ __forceinline__ float sig_(float x) { return rcp_(1.f + __expf(-x)); }
__device__ __forceinline__ float tanh_(float x) { return 1.f - 2.f * rcp_(__expf(2.f * x) + 1.f); }

__device__ __forceinline__ unsigned short bf16u(float f) {
  union { float f; unsigned u; } v; v.f = f;
  unsigned r = v.u + 0x7FFFu + ((v.u >> 16) & 1u);   // RNE
  return (unsigned short)(r >> 16);
}
__device__ __forceinline__ float bf2f(unsigned short b) {
  union { unsigned u; float f; } v; v.u = ((unsigned)b) << 16;
  return v.f;
}

__device__ __forceinline__ s8v load8(const float* __restrict__ p) {
  const float4 a = *reinterpret_cast<const float4*>(p);
  const float4 b = *reinterpret_cast<const float4*>(p + 4);
  s8v r;
  r[0] = (short)bf16u(a.x); r[1] = (short)bf16u(a.y);
  r[2] = (short)bf16u(a.z); r[3] = (short)bf16u(a.w);
  r[4] = (short)bf16u(b.x); r[5] = (short)bf16u(b.y);
  r[6] = (short)bf16u(b.z); r[7] = (short)bf16u(b.w);
  return r;
}

__device__ __forceinline__ f4v mfma16(s8v a, s8v b, f4v c) {
  return __builtin_amdgcn_mfma_f32_16x16x32_bf16(a, b, c, 0, 0, 0);
}

// LDS-only barrier: do NOT drain vmcnt (hist stores stay in flight).
__device__ __forceinline__ void barrier_lds() {
  __builtin_amdgcn_sched_barrier(0);
  asm volatile("s_waitcnt lgkmcnt(0)" ::: "memory");
  __builtin_amdgcn_s_barrier();
  __builtin_amdgcn_sched_barrier(0);
}

// ---------------------------------------------------------------------------
// K0a: gate LUT (51 distinct rank-distance inputs).
// ---------------------------------------------------------------------------
__global__ __launch_bounds__(64) void k0_gate(
    const float* __restrict__ remb,
    const float* __restrict__ rw1W, const float* __restrict__ rw1b,
    const float* __restrict__ rw2W,
    float* __restrict__ glut)
{
  const int d = threadIdx.x;
  if (d > 50) return;
  const float* er = remb + d * 32;
  float g = 0.f;
#pragma unroll
  for (int e = 0; e < 16; ++e) {
    float hs = rw1b[e];
#pragma unroll 8
    for (int i = 0; i < 32; ++i) hs += er[i] * rw1W[i * 16 + e];
    g += fmaxf(hs, 0.f) * rw2W[e];
  }
  glut[d] = sig_(g);
}

// ---------------------------------------------------------------------------
// K0b: prebuild W1 MFMA B-fragments for k2.
// ---------------------------------------------------------------------------
__global__ __launch_bounds__(256) void k0_w1(
    const float* __restrict__ W1, unsigned short* __restrict__ w1f)
{
  const int e = blockIdx.x * 256 + threadIdx.x;   // 16384 elems
  const int k = e >> 7, nn = e & 127;
  const int f = ((((nn >> 4) * 4 + (k >> 5)) * 4 + ((k >> 3) & 3)) * 16 + (nn & 15)) * 8 + (k & 7);
  w1f[f] = bf16u(W1[e]);
}

// ---------------------------------------------------------------------------
// K0c: prebuild whh1 as a LINEAR B-fragment table (128KB).
//   ushort[e*512 + lane*8 + i] = bf16(Whh1[n][k]), e=(g*8+wl)*4+kt,
//   n = g*128+16*wl+(lane&15), k = kt*32+(lane>>4)*8+i.
// ---------------------------------------------------------------------------
__global__ __launch_bounds__(256) void k0_whh1(
    const float* __restrict__ Whh1, unsigned short* __restrict__ whh1f)
{
  const int e = blockIdx.x * 256 + threadIdx.x;   // 65536 elems (512x128)
  const int n = e >> 7, k = e & 127;
  const int g = n >> 7, wl = (n >> 4) & 7, l16 = n & 15;
  const int kt = k >> 5, lq = (k >> 3) & 3, i = k & 7;
  const int dst = (((g * 8 + wl) * 4 + kt) * 64 + lq * 16 + l16) * 8 + i;
  whh1f[dst] = bf16u(Whh1[e]);
}

// ---------------------------------------------------------------------------
// K1 (round-11): wave-specialized 2-stage LSTM pipeline.
// Block = 1024 thr = 16 waves (4/SIMD forced). Group A (waves 0-7) computes
// layer-0 for step i; group B (waves 8-15) computes layer-1 for step i-1 —
// concurrently, ONE barrier per step (97 total vs 192).
// Register trick: A loads whh0 and B loads wih1 into the SAME frag[4][4]
// variable, so union allocation is 64 regs and the kernel fits the
// 128-reg/wave budget of 4 waves/SIMD. whh1 stays in the linear LDS table.
// Schedule (buffers keyed on cb = i&1):
//   start of iter i: h1s[cb] = h1[i-1], h2s[cb] = h2[i-2], xb[cb] = x[i].
//   A (i<96):  h1[i]   = L0(x[i], h1[i-1])       -> h1s[cb^1]
//   B (i>=1):  h2[i-1] = L1(h1[i-1], h2[i-2])    -> h2s[cb^1]
//   A (i>=2):  dump h2[i-2] (= h2s[cb], stable) -> hist[t=i-2]
//   epilogue:  dump h2[95] from h2s[1].
// ---------------------------------------------------------------------------
__global__ __launch_bounds__(1024) void k1_lstm_pipe(
    const float* __restrict__ x,
    const float* __restrict__ Wih0, const float* __restrict__ Whh0,
    const float* __restrict__ bih0, const float* __restrict__ bhh0,
    const float* __restrict__ Wih1, const float* __restrict__ whh1f,
    const float* __restrict__ bih1, const float* __restrict__ bhh1,
    unsigned short* __restrict__ hist)   // bf16 bits, [seq][t][unit]
{
  __shared__ __align__(16) unsigned short w1l[512 * 128];    // 128KB linear frags
  __shared__ __align__(16) unsigned short h1s[2][16 * 128];  // bf16, swizzled
  __shared__ __align__(16) unsigned short h2s[2][16 * 128];
  __shared__ __align__(16) unsigned short xb[2][16 * 32];    // A-frag layout, k>=16 zero

  const int tid  = threadIdx.x;
  const int lane = tid & 63;
  const int wv   = tid >> 6;          // wave 0..15
  const int grp  = wv >> 3;           // 0 = layer-0 group, 1 = layer-1 group
  const int wl   = wv & 7;            // wave-in-group 0..7
  const int l16  = lane & 15;
  const int lq   = lane >> 4;         // 0..3
  const int seqbase = blockIdx.x * 16;

  for (int i = tid; i < 2 * 16 * 128; i += 1024) {
    (&h1s[0][0])[i] = 0; (&h2s[0][0])[i] = 0;
  }
  if (tid < 256) {  // zero k>=16 pads of both x buffers; load x[0]
    const int s = tid >> 4, d = tid & 15;
    xb[0][s * 32 + 16 + d] = 0; xb[1][s * 32 + 16 + d] = 0;
    xb[0][s * 32 + d] = bf16u(x[((size_t)(seqbase + s) * T_ + 0) * 16 + d]);
  }
  // ---- copy prebuilt whh1 frag table -> LDS (linear, 8192 uint4 = 128KB)
  {
    const uint4* src = reinterpret_cast<const uint4*>(whh1f);
    uint4* dst = reinterpret_cast<uint4*>(w1l);
    for (int i = tid; i < 8192; i += 1024) dst[i] = src[i];
  }

  // ---- per-group register fragments: A->whh0(+wx0), B->wih1 (SHARED var!)
  s8v frag[4][4], wx0[4];
  float bias[4];
  float c[4] = {0.f, 0.f, 0.f, 0.f};
  int wb[4];
#pragma unroll
  for (int g = 0; g < 4; ++g) {
    const int gr = g * 128 + 16 * wl + l16;   // W row = gate col
    if (grp == 0) {
      bias[g] = bih0[gr] + bhh0[gr];
#pragma unroll
      for (int kt = 0; kt < 4; ++kt)
        frag[g][kt] = load8(Whh0 + (size_t)gr * 128 + kt * 32 + lq * 8);
      if (lq < 2) wx0[g] = load8(Wih0 + (size_t)gr * 16 + lq * 8);
      else { s8v z; for (int i2 = 0; i2 < 8; ++i2) z[i2] = 0; wx0[g] = z; }
      wb[g] = 0;
    } else {
      bias[g] = bih1[gr] + bhh1[gr];
#pragma unroll
      for (int kt = 0; kt < 4; ++kt)
        frag[g][kt] = load8(Wih1 + (size_t)gr * 128 + kt * 32 + lq * 8);
      wb[g] = ((g * 8 + wl) * 4) * 1024 + lane * 16;
    }
  }
  __syncthreads();

  const int sw = (l16 & 7) << 4;
  const int hunit = 16 * wl + l16;

  for (int i = 0; i <= T_; ++i) {
    const int cb = i & 1;
    if (grp == 0) {
      // ---- dump h2[i-2] (stable since last barrier) -> hist
      if (i >= 2) {
        const int seq = tid >> 5;           // 0..15 (tid < 512 in group A)
        const int u0  = (tid & 31) * 4;
        const uint2 v = *reinterpret_cast<const uint2*>(
            reinterpret_cast<const char*>(&h2s[cb][0]) + seq * 256 +
            ((2 * u0) ^ ((seq & 7) << 4)));
        *reinterpret_cast<uint2*>(
            hist + ((size_t)(seqbase + seq) * T_ + (i - 2)) * H_ + u0) = v;
      }
      if (i < T_) {
        // x prefetch for step i+1 (issue early, LDS-write after compute)
        float xv = 0.f; int xs = 0, xd = 0;
        const bool xpf = (i < T_ - 1) && (tid < 256);
        if (xpf) {
          xs = tid >> 4; xd = tid & 15;
          xv = x[((size_t)(seqbase + xs) * T_ + (i + 1)) * 16 + xd];
        }
        // ---- layer-0 MFMA
        f4v acc[4];
#pragma unroll
        for (int g = 0; g < 4; ++g) acc[g] = f4v{bias[g], bias[g], bias[g], bias[g]};
        {
          const s8v ax = *reinterpret_cast<const s8v*>(
              reinterpret_cast<const char*>(&xb[cb][0]) + l16 * 64 + lq * 16);
#pragma unroll
          for (int g = 0; g < 4; ++g) acc[g] = mfma16(ax, wx0[g], acc[g]);
        }
#pragma unroll
        for (int kt = 0; kt < 4; ++kt) {
          const s8v ah = *reinterpret_cast<const s8v*>(
              reinterpret_cast<const char*>(&h1s[cb][0]) + l16 * 256 +
              ((kt * 64 + lq * 16) ^ sw));
#pragma unroll
          for (int g = 0; g < 4; ++g) acc[g] = mfma16(ah, frag[g][kt], acc[g]);
        }
        // ---- layer-0 nonlinearity -> h1s[cb^1]
#pragma unroll
        for (int ss = 0; ss < 4; ++ss) {
          const int seq = lq * 4 + ss;
          const float iv = sig_(acc[0][ss]);
          const float fv = sig_(acc[1][ss]);
          const float gv = tanh_(acc[2][ss]);
          const float ov = sig_(acc[3][ss]);
          c[ss] = fv * c[ss] + iv * gv;
          const float hv = ov * tanh_(c[ss]);
          *reinterpret_cast<unsigned short*>(
              reinterpret_cast<char*>(&h1s[cb ^ 1][0]) + seq * 256 +
              ((2 * hunit) ^ ((seq & 7) << 4))) = bf16u(hv);
        }
        if (xpf) xb[cb ^ 1][xs * 32 + xd] = bf16u(xv);
      }
    } else {
      if (i >= 1) {
        // ---- layer-1 MFMA (wih1 in frag regs, whh1 from linear LDS)
        f4v acc[4];
#pragma unroll
        for (int g = 0; g < 4; ++g) acc[g] = f4v{bias[g], bias[g], bias[g], bias[g]};
#pragma unroll
        for (int kt = 0; kt < 4; ++kt) {
          const int ko = (kt * 64 + lq * 16) ^ sw;
          const s8v a1 = *reinterpret_cast<const s8v*>(
              reinterpret_cast<const char*>(&h1s[cb][0]) + l16 * 256 + ko);
          const s8v a2 = *reinterpret_cast<const s8v*>(
              reinterpret_cast<const char*>(&h2s[cb][0]) + l16 * 256 + ko);
#pragma unroll
          for (int g = 0; g < 4; ++g) {
            acc[g] = mfma16(a1, frag[g][kt], acc[g]);
            const s8v bw = *reinterpret_cast<const s8v*>(
                reinterpret_cast<const char*>(w1l) + wb[g] + kt * 1024);
            acc[g] = mfma16(a2, bw, acc[g]);
          }
        }
        // ---- layer-1 nonlinearity -> h2s[cb^1]
#pragma unroll
        for (int ss = 0; ss < 4; ++ss) {
          const int seq = lq * 4 + ss;
          const float iv = sig_(acc[0][ss]);
          const float fv = sig_(acc[1][ss]);
          const float gv = tanh_(acc[2][ss]);
          const float ov = sig_(acc[3][ss]);
          c[ss] = fv * c[ss] + iv * gv;
          const float hv = ov * tanh_(c[ss]);
          *reinterpret_cast<unsigned short*>(
              reinterpret_cast<char*>(&h2s[cb ^ 1][0]) + seq * 256 +
              ((2 * hunit) ^ ((seq & 7) << 4))) = bf16u(hv);
        }
      }
    }
    barrier_lds();
  }
  // ---- epilogue: dump h2[95] from h2s[1] (iter 96 wrote it; barrier passed)
  if (tid < 512) {
    const int seq = tid >> 5;
    const int u0  = (tid & 31) * 4;
    const uint2 v = *reinterpret_cast<const uint2*>(
        reinterpret_cast<const char*>(&h2s[1][0]) + seq * 256 +
        ((2 * u0) ^ ((seq & 7) << 4)));
    *reinterpret_cast<uint2*>(
        hist + ((size_t)(seqbase + seq) * T_ + (T_ - 1)) * H_ + u0) = v;
  }
}

// ---------------------------------------------------------------------------
// K2: temporal attention pooling + LN1, MFMA for the W1 GEMM.
// ---------------------------------------------------------------------------
__global__ __launch_bounds__(384, 2) void k2_pool_mfma(
    const unsigned short* __restrict__ hist,
    const unsigned short* __restrict__ w1f,   // prebuilt by k0_w1
    const float* __restrict__ attn_w,
    const float* __restrict__ W2,
    const float* __restrict__ ln1g, const float* __restrict__ ln1b,
    float* __restrict__ rep)
{
  __shared__ __align__(16) unsigned short hst[96 * 128];        // 24KB swizzled
  __shared__ float sS[128], aws[128], alpha[96], wts[96], red[128], hTs[128];
  __shared__ float ctxP[3][128];

  const int n = blockIdx.x;
  const int tid = threadIdx.x;
  const int lane = tid & 63;
  const int wv = tid >> 6;        // 0..5 == M-tile
  const int l16 = lane & 15;
  const int lq = lane >> 4;

  const unsigned short* hsrc = hist + (size_t)n * T_ * H_;
  for (int i = tid; i < 1536; i += 384) {
    const int row = i >> 4, c16 = i & 15;
    const uint4 v = *reinterpret_cast<const uint4*>(hsrc + row * 128 + c16 * 8);
    *reinterpret_cast<uint4*>(
        reinterpret_cast<char*>(hst) + row * 256 + ((c16 * 16) ^ ((row & 7) << 4))) = v;
  }
  if (tid < 128) aws[tid] = attn_w[tid];
  __syncthreads();

  if (tid < 128) hTs[tid] = bf2f(hst[95 * 128 + (tid ^ 56)]);  // row95 swizzle
  __syncthreads();
  if (tid < 128) {
    float s = 0.f;
    for (int h = 0; h < 128; ++h) s += hTs[h] * W2[(size_t)h * 128 + tid];
    sS[tid] = s;
  }
  __syncthreads();

  {
    const int row0 = wv * 16 + l16;
    f4v acc[8];
#pragma unroll
    for (int nt = 0; nt < 8; ++nt) acc[nt] = f4v{0.f, 0.f, 0.f, 0.f};
#pragma unroll
    for (int kt = 0; kt < 4; ++kt) {
      const s8v a = *reinterpret_cast<const s8v*>(
          reinterpret_cast<const char*>(hst) + row0 * 256 +
          ((kt * 64 + lq * 16) ^ ((row0 & 7) << 4)));
#pragma unroll
      for (int nt = 0; nt < 8; ++nt) {
        const s8v b = *reinterpret_cast<const s8v*>(
            w1f + ((((nt << 2) + kt) << 2 | lq) * 16 + l16) * 8);
        acc[nt] = mfma16(a, b, acc[nt]);
      }
    }
    float pa[4] = {0.f, 0.f, 0.f, 0.f};
#pragma unroll
    for (int nt = 0; nt < 8; ++nt) {
      const int col = nt * 16 + l16;
      const float ss = sS[col], aw = aws[col];
#pragma unroll
      for (int i2 = 0; i2 < 4; ++i2) pa[i2] += tanh_(acc[nt][i2] + ss) * aw;
    }
#pragma unroll
    for (int i2 = 0; i2 < 4; ++i2) {
      float v = pa[i2];
      v += __shfl_xor(v, 8); v += __shfl_xor(v, 4);
      v += __shfl_xor(v, 2); v += __shfl_xor(v, 1);
      if (l16 == 0) alpha[wv * 16 + lq * 4 + i2] = v;
    }
  }
  __syncthreads();

  if (tid < 128) red[tid] = (tid < 96) ? alpha[tid] : -1e30f;
  __syncthreads();
  for (int sft = 64; sft > 0; sft >>= 1) {
    if (tid < sft) red[tid] = fmaxf(red[tid], red[tid + sft]);
    __syncthreads();
  }
  const float mx = red[0];
  __syncthreads();
  if (tid < 128) {
    const float e = (tid < 96) ? __expf(alpha[tid] - mx) : 0.f;
    red[tid] = e;
    if (tid < 96) wts[tid] = e;
  }
  __syncthreads();
  for (int sft = 64; sft > 0; sft >>= 1) {
    if (tid < sft) red[tid] += red[tid + sft];
    __syncthreads();
  }
  const float inv = rcp_(red[0]);
  if (tid < 96) wts[tid] *= inv;
  __syncthreads();

  {
    const int th = tid >> 7, j = tid & 127;
    float cp = 0.f;
    for (int t = th * 32; t < th * 32 + 32; ++t)
      cp += wts[t] * bf2f(hst[t * 128 + (j ^ ((t & 7) << 3))]);
    ctxP[th][j] = cp;
  }
  __syncthreads();
  if (tid < 128) {
    hTs[tid] = ctxP[0][tid] + ctxP[1][tid] + ctxP[2][tid];
    red[tid] = hTs[tid];
  }
  __syncthreads();
  for (int sft = 64; sft > 0; sft >>= 1) {
    if (tid < sft) red[tid] += red[tid + sft];
    __syncthreads();
  }
  const float mean = red[0] * (1.f / 128.f);
  __syncthreads();
  if (tid < 128) { const float d = hTs[tid] - mean; red[tid] = d * d; }
  __syncthreads();
  for (int sft = 64; sft > 0; sft >>= 1) {
    if (tid < sft) red[tid] += red[tid + sft];
    __syncthreads();
  }
  const float var = red[0] * (1.f / 128.f);
  if (tid < 128)
    rep[(size_t)n * H_ + tid] =
        (hTs[tid] - mean) * rsqrtf(var + 1e-5f) * ln1g[tid] + ln1b[tid];
}

// ---------------------------------------------------------------------------
// K3: xp = rep@projW+b ; q,k,v = xp@W+b. Block = 32 rows.
// ---------------------------------------------------------------------------
__global__ __launch_bounds__(256) void k3_qkv(
    const float* __restrict__ rep,
    const float* __restrict__ projW, const float* __restrict__ projb,
    const float* __restrict__ Wq, const float* __restrict__ bq,
    const float* __restrict__ Wk, const float* __restrict__ bk,
    const float* __restrict__ Wv, const float* __restrict__ bv,
    float* __restrict__ q, float* __restrict__ k, float* __restrict__ v)
{
  const int rbase = blockIdx.x * 32;
  const int tid = threadIdx.x;
  __shared__ float reps[32][128];
  __shared__ float xps[32][64];
  for (int i = tid; i < 32 * 128; i += 256)
    reps[i >> 7][i & 127] = rep[(size_t)(rbase + (i >> 7)) * 128 + (i & 127)];
  __syncthreads();
  const int col = tid & 63, rg = tid >> 6;
#pragma unroll 2
  for (int rr = 0; rr < 8; ++rr) {
    const int r = rg * 8 + rr;
    float acc = projb[col];
    for (int kk = 0; kk < 128; ++kk) acc += reps[r][kk] * projW[kk * 64 + col];
    xps[r][col] = acc;
  }
  __syncthreads();
#pragma unroll 2
  for (int rr = 0; rr < 8; ++rr) {
    const int r = rg * 8 + rr;
    float aq = bq[col], ak = bk[col], av = bv[col];
    for (int kk = 0; kk < 64; ++kk) {
      const float xv = xps[r][kk];
      aq += xv * Wq[kk * 64 + col];
      ak += xv * Wk[kk * 64 + col];
      av += xv * Wv[kk * 64 + col];
    }
    const size_t o = (size_t)(rbase + r) * 64 + col;
    q[o] = aq; k[o] = ak; v[o] = av;
  }
}

// ---------------------------------------------------------------------------
// K4: scores + gate-LUT + softmax + attn@v. One block per (b,n) row.
// ---------------------------------------------------------------------------
__global__ __launch_bounds__(128) void k4_attn(
    const float* __restrict__ q, const float* __restrict__ kbuf, const float* __restrict__ vbuf,
    const int* __restrict__ ranks, const float* __restrict__ glut,
    float* __restrict__ ao)
{
  const int bn = blockIdx.x;
  const int b = bn >> 7;
  const int m = threadIdx.x;
  __shared__ float qs[64], attnw[128], red[128], aoP[2][64], gl[51];
  if (m < 64) qs[m] = q[(size_t)bn * 64 + m];
  if (m >= 64 && m < 64 + 51) gl[m - 64] = glut[m - 64];
  __syncthreads();
  const float* kr = kbuf + (size_t)(b * 128 + m) * 64;
  float sc = 0.f;
#pragma unroll 8
  for (int d = 0; d < 64; ++d) sc += qs[d] * kr[d];
  sc *= 0.125f;
  const int rn = ranks[bn], rm = ranks[b * 128 + m];
  int dist = rn - rm;
  if (dist < 0) dist = -dist;
  if (dist > 50) dist = 50;
  const float smv = sc * gl[dist];
  red[m] = smv;
  __syncthreads();
  for (int sft = 64; sft > 0; sft >>= 1) {
    if (m < sft) red[m] = fmaxf(red[m], red[m + sft]);
    __syncthreads();
  }
  const float mx = red[0];
  __syncthreads();
  const float e = __expf(smv - mx);
  red[m] = e;
  __syncthreads();
  for (int sft = 64; sft > 0; sft >>= 1) {
    if (m < sft) red[m] += red[m + sft];
    __syncthreads();
  }
  attnw[m] = e / red[0];
  __syncthreads();
  const int d = m & 63, half = m >> 6;
  float acc = 0.f;
  for (int mm = half * 64; mm < half * 64 + 64; ++mm)
    acc += attnw[mm] * vbuf[(size_t)(b * 128 + mm) * 64 + d];
  aoP[half][d] = acc;
  __syncthreads();
  if (m < 64) ao[(size_t)bn * 64 + m] = aoP[0][m] + aoP[1][m];
}

// ---------------------------------------------------------------------------
// K5: ff = LN(relu(ao@ff1+b)@ff2+b) ; out = sigmoid(relu(ff@sp1+b)@sp2+b).
// ---------------------------------------------------------------------------
__global__ __launch_bounds__(128) void k5_ffout(
    const float* __restrict__ ao,
    const float* __restrict__ ff1W, const float* __restrict__ ff1b,
    const float* __restrict__ ff2W, const float* __restrict__ ff2b,
    const float* __restrict__ ln2g, const float* __restrict__ ln2b,
    const float* __restrict__ sp1W, const float* __restrict__ sp1b,
    const float* __restrict__ sp2W, const float* __restrict__ sp2b,
    float* __restrict__ out)
{
  const int row = blockIdx.x;
  const int tid = threadIdx.x;
  __shared__ float aos[64], hid[128], ffs[64], red[128], h2b[32];
  if (tid < 64) aos[tid] = ao[(size_t)row * 64 + tid];
  __syncthreads();
  float hv = ff1b[tid];
  for (int dd = 0; dd < 64; ++dd) hv += aos[dd] * ff1W[dd * 128 + tid];
  hid[tid] = fmaxf(hv, 0.f);
  __syncthreads();
  float yv = 0.f;
  if (tid < 64) {
    yv = ff2b[tid];
    for (int h2 = 0; h2 < 128; ++h2) yv += hid[h2] * ff2W[h2 * 64 + tid];
  }
  red[tid] = (tid < 64) ? yv : 0.f;
  __syncthreads();
  for (int sft = 64; sft > 0; sft >>= 1) {
    if (tid < sft) red[tid] += red[tid + sft];
    __syncthreads();
  }
  const float mean = red[0] * (1.f / 64.f);
  __syncthreads();
  {
    const float d2 = (tid < 64) ? (yv - mean) : 0.f;
    red[tid] = d2 * d2;
  }
  __syncthreads();
  for (int sft = 64; sft > 0; sft >>= 1) {
    if (tid < sft) red[tid] += red[tid + sft];
    __syncthreads();
  }
  const float var = red[0] * (1.f / 64.f);
  __syncthreads();
  if (tid < 64) ffs[tid] = (yv - mean) * rsqrtf(var + 1e-5f) * ln2g[tid] + ln2b[tid];
  __syncthreads();
  if (tid < 32) {
    float h2v = sp1b[tid];
    for (int c = 0; c < 64; ++c) h2v += ffs[c] * sp1W[c * 32 + tid];
    h2b[tid] = fmaxf(h2v, 0.f);
  }
  __syncthreads();
  if (tid == 0) {
    float o = sp2b[0];
#pragma unroll
    for (int e2 = 0; e2 < 32; ++e2) o += h2b[e2] * sp2W[e2];
    out[row] = sig_(o);
  }
}

}  // namespace

extern "C" void kernel_launch(void* const* d_in, const int* in_sizes, int n_in,
                              void* d_out, int out_size, void* d_ws, size_t ws_size,
                              hipStream_t stream)
{
  const float* x      = (const float*)d_in[0];
  const int*   ranks  = (const int*)  d_in[1];
  const float* Wih0   = (const float*)d_in[2];
  const float* Whh0   = (const float*)d_in[3];
  const float* bih0   = (const float*)d_in[4];
  const float* bhh0   = (const float*)d_in[5];
  const float* Wih1   = (const float*)d_in[6];
  const float* Whh1   = (const float*)d_in[7];
  const float* bih1   = (const float*)d_in[8];
  const float* bhh1   = (const float*)d_in[9];
  const float* attn_w = (const float*)d_in[10];
  const float* W1     = (const float*)d_in[11];
  const float* W2     = (const float*)d_in[12];
  const float* ln1g   = (const float*)d_in[13];
  const float* ln1b   = (const float*)d_in[14];
  const float* projW  = (const float*)d_in[15];
  const float* projb  = (const float*)d_in[16];
  const float* Wq     = (const float*)d_in[17];
  const float* bq     = (const float*)d_in[18];
  const float* Wk     = (const float*)d_in[19];
  const float* bk     = (const float*)d_in[20];
  const float* Wv     = (const float*)d_in[21];
  const float* bv     = (const float*)d_in[22];
  const float* remb   = (const float*)d_in[23];
  const float* rw1W   = (const float*)d_in[24];
  const float* rw1b   = (const float*)d_in[25];
  const float* rw2W   = (const float*)d_in[26];
  const float* ff1W   = (const float*)d_in[27];
  const float* ff1b   = (const float*)d_in[28];
  const float* ff2W   = (const float*)d_in[29];
  const float* ff2b   = (const float*)d_in[30];
  const float* ln2g   = (const float*)d_in[31];
  const float* ln2b   = (const float*)d_in[32];
  const float* sp1W   = (const float*)d_in[33];
  const float* sp1b   = (const float*)d_in[34];
  const float* sp2W   = (const float*)d_in[35];
  const float* sp2b   = (const float*)d_in[36];
  float* out = (float*)d_out;

  char* ws = (char*)d_ws;
  unsigned short* hist = (unsigned short*)ws;            // 4096*96*128 bf16 = 96 MB
  size_t off = (size_t)4096 * 96 * 128 * 2;
  float* rep = (float*)(ws + off); off += (size_t)4096 * 128 * 4;
  float* qb  = (float*)(ws + off); off += (size_t)4096 * 64 * 4;
  float* kb  = (float*)(ws + off); off += (size_t)4096 * 64 * 4;
  float* vb  = (float*)(ws + off); off += (size_t)4096 * 64 * 4;
  float* aob = (float*)(ws + off); off += (size_t)4096 * 64 * 4;
  unsigned short* w1f   = (unsigned short*)(ws + off); off += 16384 * 2;
  float* glut = (float*)(ws + off); off += 64 * 4;
  unsigned short* whh1f = (unsigned short*)(ws + off); off += 65536 * 2;

  k0_gate<<<dim3(1), dim3(64), 0, stream>>>(remb, rw1W, rw1b, rw2W, glut);
  k0_w1<<<dim3(64), dim3(256), 0, stream>>>(W1, w1f);
  k0_whh1<<<dim3(256), dim3(256), 0, stream>>>(Whh1, whh1f);
  k1_lstm_pipe<<<dim3(256), dim3(1024), 0, stream>>>(
      x, Wih0, Whh0, bih0, bhh0, Wih1, (const float*)whh1f, bih1, bhh1, hist);
  k2_pool_mfma<<<dim3(4096), dim3(384), 0, stream>>>(
      hist, w1f, attn_w, W2, ln1g, ln1b, rep);
  k3_qkv<<<dim3(128), dim3(256), 0, stream>>>(
      rep, projW, projb, Wq, bq, Wk, bk, Wv, bv, qb, kb, vb);
  k4_attn<<<dim3(4096), dim3(128), 0, stream>>>(
      qb, kb, vb, ranks, glut, aob);
  k5_ffout<<<dim3(4096), dim3(128), 0, stream>>>(
      aob, ff1W, ff1b, ff2W, ff2b, ln2g, ln2b, sp1W, sp1b, sp2W, sp2b, out);
}

// Round 12
// 398.959 us; speedup vs baseline: 1.7300x; 1.7300x over previous
//
#include <hip/hip_runtime.h>
#include <hip/hip_bf16.h>

namespace {

constexpr int T_ = 96;
constexpr int H_ = 128;

typedef short s8v __attribute__((ext_vector_type(8)));   // 8 bf16 (4 VGPR)
typedef float f4v __attribute__((ext_vector_type(4)));   // MFMA accumulator

__device__ __forceinline__ float rcp_(float x) { return __builtin_amdgcn_rcpf(x); }
__device__ __forceinline__ float sig_(float x) { return rcp_(1.f + __expf(-x)); }
__device__ __forceinline__ float tanh_(float x) { return 1.f - 2.f * rcp_(__expf(2.f * x) + 1.f); }

__device__ __forceinline__ unsigned short bf16u(float f) {
  union { float f; unsigned u; } v; v.f = f;
  unsigned r = v.u + 0x7FFFu + ((v.u >> 16) & 1u);   // RNE
  return (unsigned short)(r >> 16);
}
__device__ __forceinline__ float bf2f(unsigned short b) {
  union { unsigned u; float f; } v; v.u = ((unsigned)b) << 16;
  return v.f;
}

__device__ __forceinline__ s8v load8(const float* __restrict__ p) {
  const float4 a = *reinterpret_cast<const float4*>(p);
  const float4 b = *reinterpret_cast<const float4*>(p + 4);
  s8v r;
  r[0] = (short)bf16u(a.x); r[1] = (short)bf16u(a.y);
  r[2] = (short)bf16u(a.z); r[3] = (short)bf16u(a.w);
  r[4] = (short)bf16u(b.x); r[5] = (short)bf16u(b.y);
  r[6] = (short)bf16u(b.z); r[7] = (short)bf16u(b.w);
  return r;
}

__device__ __forceinline__ f4v mfma16(s8v a, s8v b, f4v c) {
  return __builtin_amdgcn_mfma_f32_16x16x32_bf16(a, b, c, 0, 0, 0);
}

// LDS-only barrier: do NOT drain vmcnt (hist stores stay in flight).
__device__ __forceinline__ void barrier_lds() {
  __builtin_amdgcn_sched_barrier(0);
  asm volatile("s_waitcnt lgkmcnt(0)" ::: "memory");
  __builtin_amdgcn_s_barrier();
  __builtin_amdgcn_sched_barrier(0);
}

// ---------------------------------------------------------------------------
// K0a: gate LUT (51 distinct rank-distance inputs).
// ---------------------------------------------------------------------------
__global__ __launch_bounds__(64) void k0_gate(
    const float* __restrict__ remb,
    const float* __restrict__ rw1W, const float* __restrict__ rw1b,
    const float* __restrict__ rw2W,
    float* __restrict__ glut)
{
  const int d = threadIdx.x;
  if (d > 50) return;
  const float* er = remb + d * 32;
  float g = 0.f;
#pragma unroll
  for (int e = 0; e < 16; ++e) {
    float hs = rw1b[e];
#pragma unroll 8
    for (int i = 0; i < 32; ++i) hs += er[i] * rw1W[i * 16 + e];
    g += fmaxf(hs, 0.f) * rw2W[e];
  }
  glut[d] = sig_(g);
}

// ---------------------------------------------------------------------------
// K0b: prebuild W1 MFMA B-fragments for k2.
// ---------------------------------------------------------------------------
__global__ __launch_bounds__(256) void k0_w1(
    const float* __restrict__ W1, unsigned short* __restrict__ w1f)
{
  const int e = blockIdx.x * 256 + threadIdx.x;   // 16384 elems
  const int k = e >> 7, nn = e & 127;
  const int f = ((((nn >> 4) * 4 + (k >> 5)) * 4 + ((k >> 3) & 3)) * 16 + (nn & 15)) * 8 + (k & 7);
  w1f[f] = bf16u(W1[e]);
}

// ---------------------------------------------------------------------------
// K0c: prebuild whh1 as a LINEAR B-fragment table (128KB).
// ---------------------------------------------------------------------------
__global__ __launch_bounds__(256) void k0_whh1(
    const float* __restrict__ Whh1, unsigned short* __restrict__ whh1f)
{
  const int e = blockIdx.x * 256 + threadIdx.x;   // 65536 elems (512x128)
  const int n = e >> 7, k = e & 127;
  const int g = n >> 7, wl = (n >> 4) & 7, l16 = n & 15;
  const int kt = k >> 5, lq = (k >> 3) & 3, i = k & 7;
  const int dst = (((g * 8 + wl) * 4 + kt) * 64 + lq * 16 + l16) * 8 + i;
  whh1f[dst] = bf16u(Whh1[e]);
}

// ---------------------------------------------------------------------------
// K1: two-layer LSTM via MFMA — EXACT round-10 kernel (282us, verified).
// r11's 16-wave pipeline spilled (961MB FETCH) — 2 waves/SIMD is the floor
// for this register state; k1 is frozen here.
// ---------------------------------------------------------------------------
__global__ __launch_bounds__(512) void k1_lstm_mfma(
    const float* __restrict__ x,
    const float* __restrict__ Wih0, const float* __restrict__ Whh0,
    const float* __restrict__ bih0, const float* __restrict__ bhh0,
    const float* __restrict__ Wih1, const float* __restrict__ whh1f,
    const float* __restrict__ bih1, const float* __restrict__ bhh1,
    unsigned short* __restrict__ hist)   // bf16 bits, [seq][t][unit]
{
  __shared__ __align__(16) unsigned short w1l[512 * 128];    // 128KB linear frags
  __shared__ __align__(16) unsigned short h1s[2][16 * 128];  // bf16, swizzled
  __shared__ __align__(16) unsigned short h2s[2][16 * 128];
  __shared__ __align__(16) unsigned short xb[2][16 * 32];    // A-frag layout, k>=16 zero

  const int tid  = threadIdx.x;
  const int lane = tid & 63;
  const int wv   = tid >> 6;          // wave 0..7
  const int l16  = lane & 15;
  const int lq   = lane >> 4;         // 0..3
  const int seqbase = blockIdx.x * 16;

  for (int i = tid; i < 2 * 16 * 128; i += 512) {
    (&h1s[0][0])[i] = 0; (&h2s[0][0])[i] = 0;
  }
  if (tid < 256) {  // zero the k>=16 pad of both x buffers
    const int s = tid >> 4, d = tid & 15;
    xb[0][s * 32 + 16 + d] = 0; xb[1][s * 32 + 16 + d] = 0;
    xb[0][s * 32 + d] = bf16u(x[((size_t)(seqbase + s) * T_ + 0) * 16 + d]);
  }
  {
    const uint4* src = reinterpret_cast<const uint4*>(whh1f);
    uint4* dst = reinterpret_cast<uint4*>(w1l);
    for (int i = tid; i < 8192; i += 512) dst[i] = src[i];
  }

  s8v whh0[4][4], wih1[4][4], wx0[4];
  float b0[4], b1[4];
  int wb[4];
#pragma unroll
  for (int g = 0; g < 4; ++g) {
    const int gr = g * 128 + 16 * wv + l16;   // W row = gate col
    b0[g] = bih0[gr] + bhh0[gr];
    b1[g] = bih1[gr] + bhh1[gr];
    wb[g] = ((g * 8 + wv) * 4) * 1024 + lane * 16;
#pragma unroll
    for (int kt = 0; kt < 4; ++kt) {
      const int k0 = kt * 32 + lq * 8;
      whh0[g][kt] = load8(Whh0 + (size_t)gr * 128 + k0);
      wih1[g][kt] = load8(Wih1 + (size_t)gr * 128 + k0);
    }
    if (lq < 2) wx0[g] = load8(Wih0 + (size_t)gr * 16 + lq * 8);
    else { s8v z; for (int i2 = 0; i2 < 8; ++i2) z[i2] = 0; wx0[g] = z; }
  }

  float c1[4] = {0.f, 0.f, 0.f, 0.f}, c2[4] = {0.f, 0.f, 0.f, 0.f};
  int cur = 0;
  __syncthreads();

  const int sw = (l16 & 7) << 4;
  const int hunit = 16 * wv + l16;

  for (int t = 0; t < T_; ++t) {
    const int xc = t & 1;
    float xv = 0.f;
    const bool xpf = (t + 1 < T_) && (tid < 256);
    if (xpf) {
      const int s = tid >> 4, d = tid & 15;
      xv = x[((size_t)(seqbase + s) * T_ + (t + 1)) * 16 + d];
    }

    // ================= layer-0 MFMA =================
    f4v acc[4];
#pragma unroll
    for (int g = 0; g < 4; ++g) acc[g] = f4v{b0[g], b0[g], b0[g], b0[g]};
    {
      const s8v ax = *reinterpret_cast<const s8v*>(
          reinterpret_cast<const char*>(&xb[xc][0]) + l16 * 64 + lq * 16);
#pragma unroll
      for (int g = 0; g < 4; ++g) acc[g] = mfma16(ax, wx0[g], acc[g]);
    }
#pragma unroll
    for (int kt = 0; kt < 4; ++kt) {
      const s8v ah = *reinterpret_cast<const s8v*>(
          reinterpret_cast<const char*>(&h1s[cur][0]) + l16 * 256 +
          ((kt * 64 + lq * 16) ^ sw));
#pragma unroll
      for (int g = 0; g < 4; ++g) acc[g] = mfma16(ah, whh0[g][kt], acc[g]);
    }
#pragma unroll
    for (int ss = 0; ss < 4; ++ss) {
      const int seq = lq * 4 + ss;
      const float iv = sig_(acc[0][ss]);
      const float fv = sig_(acc[1][ss]);
      const float gv = tanh_(acc[2][ss]);
      const float ov = sig_(acc[3][ss]);
      c1[ss] = fv * c1[ss] + iv * gv;
      const float hv = ov * tanh_(c1[ss]);
      *reinterpret_cast<unsigned short*>(
          reinterpret_cast<char*>(&h1s[cur ^ 1][0]) + seq * 256 +
          ((2 * hunit) ^ ((seq & 7) << 4))) = bf16u(hv);
    }
    barrier_lds();

    // ================= layer-1 MFMA =================
#pragma unroll
    for (int g = 0; g < 4; ++g) acc[g] = f4v{b1[g], b1[g], b1[g], b1[g]};
#pragma unroll
    for (int kt = 0; kt < 4; ++kt) {
      const int ko = (kt * 64 + lq * 16) ^ sw;
      const s8v a1 = *reinterpret_cast<const s8v*>(
          reinterpret_cast<const char*>(&h1s[cur ^ 1][0]) + l16 * 256 + ko);
      const s8v a2 = *reinterpret_cast<const s8v*>(
          reinterpret_cast<const char*>(&h2s[cur][0]) + l16 * 256 + ko);
#pragma unroll
      for (int g = 0; g < 4; ++g) {
        acc[g] = mfma16(a1, wih1[g][kt], acc[g]);
        const s8v bw = *reinterpret_cast<const s8v*>(
            reinterpret_cast<const char*>(w1l) + wb[g] + kt * 1024);
        acc[g] = mfma16(a2, bw, acc[g]);
      }
    }
#pragma unroll
    for (int ss = 0; ss < 4; ++ss) {
      const int seq = lq * 4 + ss;
      const float iv = sig_(acc[0][ss]);
      const float fv = sig_(acc[1][ss]);
      const float gv = tanh_(acc[2][ss]);
      const float ov = sig_(acc[3][ss]);
      c2[ss] = fv * c2[ss] + iv * gv;
      const float hv = ov * tanh_(c2[ss]);
      *reinterpret_cast<unsigned short*>(
          reinterpret_cast<char*>(&h2s[cur ^ 1][0]) + seq * 256 +
          ((2 * hunit) ^ ((seq & 7) << 4))) = bf16u(hv);
    }
    if (xpf) {
      const int s = tid >> 4, d = tid & 15;
      xb[xc ^ 1][s * 32 + d] = bf16u(xv);
    }
    barrier_lds();

    {
      const int seq = tid >> 5;
      const int u0  = (tid & 31) * 4;
      const uint2 v = *reinterpret_cast<const uint2*>(
          reinterpret_cast<const char*>(&h2s[cur ^ 1][0]) + seq * 256 +
          ((2 * u0) ^ ((seq & 7) << 4)));
      *reinterpret_cast<uint2*>(
          hist + ((size_t)(seqbase + seq) * T_ + t) * H_ + u0) = v;
    }
    cur ^= 1;
  }
}

// ---------------------------------------------------------------------------
// K2: temporal attention pooling + LN1, MFMA for the W1 GEMM.
// ---------------------------------------------------------------------------
__global__ __launch_bounds__(384, 2) void k2_pool_mfma(
    const unsigned short* __restrict__ hist,
    const unsigned short* __restrict__ w1f,
    const float* __restrict__ attn_w,
    const float* __restrict__ W2,
    const float* __restrict__ ln1g, const float* __restrict__ ln1b,
    float* __restrict__ rep)
{
  __shared__ __align__(16) unsigned short hst[96 * 128];
  __shared__ float sS[128], aws[128], alpha[96], wts[96], red[128], hTs[128];
  __shared__ float ctxP[3][128];

  const int n = blockIdx.x;
  const int tid = threadIdx.x;
  const int lane = tid & 63;
  const int wv = tid >> 6;
  const int l16 = lane & 15;
  const int lq = lane >> 4;

  const unsigned short* hsrc = hist + (size_t)n * T_ * H_;
  for (int i = tid; i < 1536; i += 384) {
    const int row = i >> 4, c16 = i & 15;
    const uint4 v = *reinterpret_cast<const uint4*>(hsrc + row * 128 + c16 * 8);
    *reinterpret_cast<uint4*>(
        reinterpret_cast<char*>(hst) + row * 256 + ((c16 * 16) ^ ((row & 7) << 4))) = v;
  }
  if (tid < 128) aws[tid] = attn_w[tid];
  __syncthreads();

  if (tid < 128) hTs[tid] = bf2f(hst[95 * 128 + (tid ^ 56)]);
  __syncthreads();
  if (tid < 128) {
    float s = 0.f;
    for (int h = 0; h < 128; ++h) s += hTs[h] * W2[(size_t)h * 128 + tid];
    sS[tid] = s;
  }
  __syncthreads();

  {
    const int row0 = wv * 16 + l16;
    f4v acc[8];
#pragma unroll
    for (int nt = 0; nt < 8; ++nt) acc[nt] = f4v{0.f, 0.f, 0.f, 0.f};
#pragma unroll
    for (int kt = 0; kt < 4; ++kt) {
      const s8v a = *reinterpret_cast<const s8v*>(
          reinterpret_cast<const char*>(hst) + row0 * 256 +
          ((kt * 64 + lq * 16) ^ ((row0 & 7) << 4)));
#pragma unroll
      for (int nt = 0; nt < 8; ++nt) {
        const s8v b = *reinterpret_cast<const s8v*>(
            w1f + ((((nt << 2) + kt) << 2 | lq) * 16 + l16) * 8);
        acc[nt] = mfma16(a, b, acc[nt]);
      }
    }
    float pa[4] = {0.f, 0.f, 0.f, 0.f};
#pragma unroll
    for (int nt = 0; nt < 8; ++nt) {
      const int col = nt * 16 + l16;
      const float ss = sS[col], aw = aws[col];
#pragma unroll
      for (int i2 = 0; i2 < 4; ++i2) pa[i2] += tanh_(acc[nt][i2] + ss) * aw;
    }
#pragma unroll
    for (int i2 = 0; i2 < 4; ++i2) {
      float v = pa[i2];
      v += __shfl_xor(v, 8); v += __shfl_xor(v, 4);
      v += __shfl_xor(v, 2); v += __shfl_xor(v, 1);
      if (l16 == 0) alpha[wv * 16 + lq * 4 + i2] = v;
    }
  }
  __syncthreads();

  if (tid < 128) red[tid] = (tid < 96) ? alpha[tid] : -1e30f;
  __syncthreads();
  for (int sft = 64; sft > 0; sft >>= 1) {
    if (tid < sft) red[tid] = fmaxf(red[tid], red[tid + sft]);
    __syncthreads();
  }
  const float mx = red[0];
  __syncthreads();
  if (tid < 128) {
    const float e = (tid < 96) ? __expf(alpha[tid] - mx) : 0.f;
    red[tid] = e;
    if (tid < 96) wts[tid] = e;
  }
  __syncthreads();
  for (int sft = 64; sft > 0; sft >>= 1) {
    if (tid < sft) red[tid] += red[tid + sft];
    __syncthreads();
  }
  const float inv = rcp_(red[0]);
  if (tid < 96) wts[tid] *= inv;
  __syncthreads();

  {
    const int th = tid >> 7, j = tid & 127;
    float cp = 0.f;
    for (int t = th * 32; t < th * 32 + 32; ++t)
      cp += wts[t] * bf2f(hst[t * 128 + (j ^ ((t & 7) << 3))]);
    ctxP[th][j] = cp;
  }
  __syncthreads();
  if (tid < 128) {
    hTs[tid] = ctxP[0][tid] + ctxP[1][tid] + ctxP[2][tid];
    red[tid] = hTs[tid];
  }
  __syncthreads();
  for (int sft = 64; sft > 0; sft >>= 1) {
    if (tid < sft) red[tid] += red[tid + sft];
    __syncthreads();
  }
  const float mean = red[0] * (1.f / 128.f);
  __syncthreads();
  if (tid < 128) { const float d = hTs[tid] - mean; red[tid] = d * d; }
  __syncthreads();
  for (int sft = 64; sft > 0; sft >>= 1) {
    if (tid < sft) red[tid] += red[tid + sft];
    __syncthreads();
  }
  const float var = red[0] * (1.f / 128.f);
  if (tid < 128)
    rep[(size_t)n * H_ + tid] =
        (hTs[tid] - mean) * rsqrtf(var + 1e-5f) * ln1g[tid] + ln1b[tid];
}

// ---------------------------------------------------------------------------
// K3: xp = rep@projW+b ; q,k,v = xp@W+b. Block = 32 rows.
// ---------------------------------------------------------------------------
__global__ __launch_bounds__(256) void k3_qkv(
    const float* __restrict__ rep,
    const float* __restrict__ projW, const float* __restrict__ projb,
    const float* __restrict__ Wq, const float* __restrict__ bq,
    const float* __restrict__ Wk, const float* __restrict__ bk,
    const float* __restrict__ Wv, const float* __restrict__ bv,
    float* __restrict__ q, float* __restrict__ k, float* __restrict__ v)
{
  const int rbase = blockIdx.x * 32;
  const int tid = threadIdx.x;
  __shared__ float reps[32][128];
  __shared__ float xps[32][64];
  for (int i = tid; i < 32 * 128; i += 256)
    reps[i >> 7][i & 127] = rep[(size_t)(rbase + (i >> 7)) * 128 + (i & 127)];
  __syncthreads();
  const int col = tid & 63, rg = tid >> 6;
#pragma unroll 2
  for (int rr = 0; rr < 8; ++rr) {
    const int r = rg * 8 + rr;
    float acc = projb[col];
    for (int kk = 0; kk < 128; ++kk) acc += reps[r][kk] * projW[kk * 64 + col];
    xps[r][col] = acc;
  }
  __syncthreads();
#pragma unroll 2
  for (int rr = 0; rr < 8; ++rr) {
    const int r = rg * 8 + rr;
    float aq = bq[col], ak = bk[col], av = bv[col];
    for (int kk = 0; kk < 64; ++kk) {
      const float xv = xps[r][kk];
      aq += xv * Wq[kk * 64 + col];
      ak += xv * Wk[kk * 64 + col];
      av += xv * Wv[kk * 64 + col];
    }
    const size_t o = (size_t)(rbase + r) * 64 + col;
    q[o] = aq; k[o] = ak; v[o] = av;
  }
}

// ---------------------------------------------------------------------------
// K4 (round-12): batched attention. Block = one (b, 16-row group), 512 thr.
// Stages K,V of batch b into padded LDS ([128][65] -> conflict-free), gate
// LUT + ranks in LDS. Each wave owns 2 rows: scores via per-lane dots (2 keys
// per lane), wave-shuffle softmax, PV via per-lane output column. No block
// barriers inside the row loop; K/V read from HBM/L2 once per 16 rows
// instead of once per row (16x traffic cut vs r11 k4).
// ---------------------------------------------------------------------------
__global__ __launch_bounds__(512) void k4_attn_b(
    const float* __restrict__ q, const float* __restrict__ kbuf,
    const float* __restrict__ vbuf,
    const int* __restrict__ ranks, const float* __restrict__ glut,
    float* __restrict__ ao)
{
  __shared__ float Ks[128][65], Vs[128][65];   // +1 pad: scores read is 2-way
  __shared__ float qs[16][64];
  __shared__ float wrow[8][128];
  __shared__ float gl[51];
  __shared__ int rs[128];

  const int tid = threadIdx.x, lane = tid & 63, wv = tid >> 6;
  const int b = blockIdx.x >> 3;              // batch 0..31
  const int rowbase = (blockIdx.x & 7) * 16;  // local n base within b

  // ---- stage K, V (linear index i == b-local element), q rows, LUTs
  for (int i = tid; i < 8192; i += 512) {
    Ks[i >> 6][i & 63] = kbuf[(size_t)b * 8192 + i];
    Vs[i >> 6][i & 63] = vbuf[(size_t)b * 8192 + i];
  }
  for (int i = tid; i < 1024; i += 512)
    qs[i >> 6][i & 63] = q[((size_t)b * 128 + rowbase) * 64 + i];
  if (tid < 128) rs[tid] = ranks[b * 128 + tid];
  if (tid >= 128 && tid < 179) gl[tid - 128] = glut[tid - 128];
  __syncthreads();

  const int m0 = lane, m1 = lane + 64;
#pragma unroll
  for (int rr = 0; rr < 2; ++rr) {
    const int lr = wv * 2 + rr;               // local row 0..15
    const int rn = rs[rowbase + lr];
    // ---- scores: this lane's two keys
    float s0 = 0.f, s1 = 0.f;
#pragma unroll 8
    for (int d = 0; d < 64; ++d) {
      const float qd = qs[lr][d];
      s0 += qd * Ks[m0][d];
      s1 += qd * Ks[m1][d];
    }
    int d0 = rn - rs[m0]; if (d0 < 0) d0 = -d0; if (d0 > 50) d0 = 50;
    int d1 = rn - rs[m1]; if (d1 < 0) d1 = -d1; if (d1 > 50) d1 = 50;
    s0 *= 0.125f * gl[d0];
    s1 *= 0.125f * gl[d1];
    // ---- wave softmax over 128 values (2/lane)
    float mx = fmaxf(s0, s1);
#pragma unroll
    for (int off = 32; off; off >>= 1) mx = fmaxf(mx, __shfl_xor(mx, off));
    const float e0 = __expf(s0 - mx), e1 = __expf(s1 - mx);
    float sum = e0 + e1;
#pragma unroll
    for (int off = 32; off; off >>= 1) sum += __shfl_xor(sum, off);
    const float inv = rcp_(sum);
    wrow[wv][m0] = e0 * inv;
    wrow[wv][m1] = e1 * inv;
    asm volatile("s_waitcnt lgkmcnt(0)" ::: "memory");
    // ---- PV: lane owns output column `lane`
    float acc = 0.f;
#pragma unroll 4
    for (int m = 0; m < 128; ++m) acc += wrow[wv][m] * Vs[m][lane];
    ao[((size_t)b * 128 + rowbase + lr) * 64 + lane] = acc;
  }
}

// ---------------------------------------------------------------------------
// K5: ff = LN(relu(ao@ff1+b)@ff2+b) ; out = sigmoid(relu(ff@sp1+b)@sp2+b).
// ---------------------------------------------------------------------------
__global__ __launch_bounds__(128) void k5_ffout(
    const float* __restrict__ ao,
    const float* __restrict__ ff1W, const float* __restrict__ ff1b,
    const float* __restrict__ ff2W, const float* __restrict__ ff2b,
    const float* __restrict__ ln2g, const float* __restrict__ ln2b,
    const float* __restrict__ sp1W, const float* __restrict__ sp1b,
    const float* __restrict__ sp2W, const float* __restrict__ sp2b,
    float* __restrict__ out)
{
  const int row = blockIdx.x;
  const int tid = threadIdx.x;
  __shared__ float aos[64], hid[128], ffs[64], red[128], h2b[32];
  if (tid < 64) aos[tid] = ao[(size_t)row * 64 + tid];
  __syncthreads();
  float hv = ff1b[tid];
  for (int dd = 0; dd < 64; ++dd) hv += aos[dd] * ff1W[dd * 128 + tid];
  hid[tid] = fmaxf(hv, 0.f);
  __syncthreads();
  float yv = 0.f;
  if (tid < 64) {
    yv = ff2b[tid];
    for (int h2 = 0; h2 < 128; ++h2) yv += hid[h2] * ff2W[h2 * 64 + tid];
  }
  red[tid] = (tid < 64) ? yv : 0.f;
  __syncthreads();
  for (int sft = 64; sft > 0; sft >>= 1) {
    if (tid < sft) red[tid] += red[tid + sft];
    __syncthreads();
  }
  const float mean = red[0] * (1.f / 64.f);
  __syncthreads();
  {
    const float d2 = (tid < 64) ? (yv - mean) : 0.f;
    red[tid] = d2 * d2;
  }
  __syncthreads();
  for (int sft = 64; sft > 0; sft >>= 1) {
    if (tid < sft) red[tid] += red[tid + sft];
    __syncthreads();
  }
  const float var = red[0] * (1.f / 64.f);
  __syncthreads();
  if (tid < 64) ffs[tid] = (yv - mean) * rsqrtf(var + 1e-5f) * ln2g[tid] + ln2b[tid];
  __syncthreads();
  if (tid < 32) {
    float h2v = sp1b[tid];
    for (int c = 0; c < 64; ++c) h2v += ffs[c] * sp1W[c * 32 + tid];
    h2b[tid] = fmaxf(h2v, 0.f);
  }
  __syncthreads();
  if (tid == 0) {
    float o = sp2b[0];
#pragma unroll
    for (int e2 = 0; e2 < 32; ++e2) o += h2b[e2] * sp2W[e2];
    out[row] = sig_(o);
  }
}

}  // namespace

extern "C" void kernel_launch(void* const* d_in, const int* in_sizes, int n_in,
                              void* d_out, int out_size, void* d_ws, size_t ws_size,
                              hipStream_t stream)
{
  const float* x      = (const float*)d_in[0];
  const int*   ranks  = (const int*)  d_in[1];
  const float* Wih0   = (const float*)d_in[2];
  const float* Whh0   = (const float*)d_in[3];
  const float* bih0   = (const float*)d_in[4];
  const float* bhh0   = (const float*)d_in[5];
  const float* Wih1   = (const float*)d_in[6];
  const float* Whh1   = (const float*)d_in[7];
  const float* bih1   = (const float*)d_in[8];
  const float* bhh1   = (const float*)d_in[9];
  const float* attn_w = (const float*)d_in[10];
  const float* W1     = (const float*)d_in[11];
  const float* W2     = (const float*)d_in[12];
  const float* ln1g   = (const float*)d_in[13];
  const float* ln1b   = (const float*)d_in[14];
  const float* projW  = (const float*)d_in[15];
  const float* projb  = (const float*)d_in[16];
  const float* Wq     = (const float*)d_in[17];
  const float* bq     = (const float*)d_in[18];
  const float* Wk     = (const float*)d_in[19];
  const float* bk     = (const float*)d_in[20];
  const float* Wv     = (const float*)d_in[21];
  const float* bv     = (const float*)d_in[22];
  const float* remb   = (const float*)d_in[23];
  const float* rw1W   = (const float*)d_in[24];
  const float* rw1b   = (const float*)d_in[25];
  const float* rw2W   = (const float*)d_in[26];
  const float* ff1W   = (const float*)d_in[27];
  const float* ff1b   = (const float*)d_in[28];
  const float* ff2W   = (const float*)d_in[29];
  const float* ff2b   = (const float*)d_in[30];
  const float* ln2g   = (const float*)d_in[31];
  const float* ln2b   = (const float*)d_in[32];
  const float* sp1W   = (const float*)d_in[33];
  const float* sp1b   = (const float*)d_in[34];
  const float* sp2W   = (const float*)d_in[35];
  const float* sp2b   = (const float*)d_in[36];
  float* out = (float*)d_out;

  char* ws = (char*)d_ws;
  unsigned short* hist = (unsigned short*)ws;            // 4096*96*128 bf16 = 96 MB
  size_t off = (size_t)4096 * 96 * 128 * 2;
  float* rep = (float*)(ws + off); off += (size_t)4096 * 128 * 4;
  float* qb  = (float*)(ws + off); off += (size_t)4096 * 64 * 4;
  float* kb  = (float*)(ws + off); off += (size_t)4096 * 64 * 4;
  float* vb  = (float*)(ws + off); off += (size_t)4096 * 64 * 4;
  float* aob = (float*)(ws + off); off += (size_t)4096 * 64 * 4;
  unsigned short* w1f   = (unsigned short*)(ws + off); off += 16384 * 2;
  float* glut = (float*)(ws + off); off += 64 * 4;
  unsigned short* whh1f = (unsigned short*)(ws + off); off += 65536 * 2;

  k0_gate<<<dim3(1), dim3(64), 0, stream>>>(remb, rw1W, rw1b, rw2W, glut);
  k0_w1<<<dim3(64), dim3(256), 0, stream>>>(W1, w1f);
  k0_whh1<<<dim3(256), dim3(256), 0, stream>>>(Whh1, whh1f);
  k1_lstm_mfma<<<dim3(256), dim3(512), 0, stream>>>(
      x, Wih0, Whh0, bih0, bhh0, Wih1, (const float*)whh1f, bih1, bhh1, hist);
  k2_pool_mfma<<<dim3(4096), dim3(384), 0, stream>>>(
      hist, w1f, attn_w, W2, ln1g, ln1b, rep);
  k3_qkv<<<dim3(128), dim3(256), 0, stream>>>(
      rep, projW, projb, Wq, bq, Wk, bk, Wv, bv, qb, kb, vb);
  k4_attn_b<<<dim3(256), dim3(512), 0, stream>>>(
      qb, kb, vb, ranks, glut, aob);
  k5_ffout<<<dim3(4096), dim3(128), 0, stream>>>(
      aob, ff1W, ff1b, ff2W, ff2b, ln2g, ln2b, sp1W, sp1b, sp2W, sp2b, out);
}

// Round 13
// 393.645 us; speedup vs baseline: 1.7534x; 1.0135x over previous
//
#include <hip/hip_runtime.h>
#include <hip/hip_bf16.h>

namespace {

constexpr int T_ = 96;
constexpr int H_ = 128;

typedef short s8v __attribute__((ext_vector_type(8)));   // 8 bf16 (4 VGPR)
typedef float f4v __attribute__((ext_vector_type(4)));   // MFMA accumulator

__device__ __forceinline__ float rcp_(float x) { return __builtin_amdgcn_rcpf(x); }
__device__ __forceinline__ float sig_(float x) { return rcp_(1.f + __expf(-x)); }
__device__ __forceinline__ float tanh_(float x) { return 1.f - 2.f * rcp_(__expf(2.f * x) + 1.f); }

__device__ __forceinline__ unsigned short bf16u(float f) {
  union { float f; unsigned u; } v; v.f = f;
  unsigned r = v.u + 0x7FFFu + ((v.u >> 16) & 1u);   // RNE
  return (unsigned short)(r >> 16);
}
__device__ __forceinline__ float bf2f(unsigned short b) {
  union { unsigned u; float f; } v; v.u = ((unsigned)b) << 16;
  return v.f;
}

__device__ __forceinline__ s8v load8(const float* __restrict__ p) {
  const float4 a = *reinterpret_cast<const float4*>(p);
  const float4 b = *reinterpret_cast<const float4*>(p + 4);
  s8v r;
  r[0] = (short)bf16u(a.x); r[1] = (short)bf16u(a.y);
  r[2] = (short)bf16u(a.z); r[3] = (short)bf16u(a.w);
  r[4] = (short)bf16u(b.x); r[5] = (short)bf16u(b.y);
  r[6] = (short)bf16u(b.z); r[7] = (short)bf16u(b.w);
  return r;
}

__device__ __forceinline__ f4v mfma16(s8v a, s8v b, f4v c) {
  return __builtin_amdgcn_mfma_f32_16x16x32_bf16(a, b, c, 0, 0, 0);
}

// LDS-only barrier: do NOT drain vmcnt (hist stores stay in flight).
__device__ __forceinline__ void barrier_lds() {
  __builtin_amdgcn_sched_barrier(0);
  asm volatile("s_waitcnt lgkmcnt(0)" ::: "memory");
  __builtin_amdgcn_s_barrier();
  __builtin_amdgcn_sched_barrier(0);
}

// ---------------------------------------------------------------------------
// K0a: gate LUT (51 distinct rank-distance inputs).
// ---------------------------------------------------------------------------
__global__ __launch_bounds__(64) void k0_gate(
    const float* __restrict__ remb,
    const float* __restrict__ rw1W, const float* __restrict__ rw1b,
    const float* __restrict__ rw2W,
    float* __restrict__ glut)
{
  const int d = threadIdx.x;
  if (d > 50) return;
  const float* er = remb + d * 32;
  float g = 0.f;
#pragma unroll
  for (int e = 0; e < 16; ++e) {
    float hs = rw1b[e];
#pragma unroll 8
    for (int i = 0; i < 32; ++i) hs += er[i] * rw1W[i * 16 + e];
    g += fmaxf(hs, 0.f) * rw2W[e];
  }
  glut[d] = sig_(g);
}

// ---------------------------------------------------------------------------
// K0b: prebuild W1 MFMA B-fragments for k2.
// ---------------------------------------------------------------------------
__global__ __launch_bounds__(256) void k0_w1(
    const float* __restrict__ W1, unsigned short* __restrict__ w1f)
{
  const int e = blockIdx.x * 256 + threadIdx.x;   // 16384 elems
  const int k = e >> 7, nn = e & 127;
  const int f = ((((nn >> 4) * 4 + (k >> 5)) * 4 + ((k >> 3) & 3)) * 16 + (nn & 15)) * 8 + (k & 7);
  w1f[f] = bf16u(W1[e]);
}

// ---------------------------------------------------------------------------
// K0c: prebuild whh1 as a LINEAR B-fragment table (128KB).
// ---------------------------------------------------------------------------
__global__ __launch_bounds__(256) void k0_whh1(
    const float* __restrict__ Whh1, unsigned short* __restrict__ whh1f)
{
  const int e = blockIdx.x * 256 + threadIdx.x;   // 65536 elems (512x128)
  const int n = e >> 7, k = e & 127;
  const int g = n >> 7, wl = (n >> 4) & 7, l16 = n & 15;
  const int kt = k >> 5, lq = (k >> 3) & 3, i = k & 7;
  const int dst = (((g * 8 + wl) * 4 + kt) * 64 + lq * 16 + l16) * 8 + i;
  whh1f[dst] = bf16u(Whh1[e]);
}

// ---------------------------------------------------------------------------
// K1: two-layer LSTM via MFMA — frozen (282us, verified floor for this
// decomposition: 2 waves/SIMD register-locked, 75% combined issue util).
// ---------------------------------------------------------------------------
__global__ __launch_bounds__(512) void k1_lstm_mfma(
    const float* __restrict__ x,
    const float* __restrict__ Wih0, const float* __restrict__ Whh0,
    const float* __restrict__ bih0, const float* __restrict__ bhh0,
    const float* __restrict__ Wih1, const float* __restrict__ whh1f,
    const float* __restrict__ bih1, const float* __restrict__ bhh1,
    unsigned short* __restrict__ hist)   // bf16 bits, [seq][t][unit]
{
  __shared__ __align__(16) unsigned short w1l[512 * 128];    // 128KB linear frags
  __shared__ __align__(16) unsigned short h1s[2][16 * 128];  // bf16, swizzled
  __shared__ __align__(16) unsigned short h2s[2][16 * 128];
  __shared__ __align__(16) unsigned short xb[2][16 * 32];    // A-frag layout, k>=16 zero

  const int tid  = threadIdx.x;
  const int lane = tid & 63;
  const int wv   = tid >> 6;          // wave 0..7
  const int l16  = lane & 15;
  const int lq   = lane >> 4;         // 0..3
  const int seqbase = blockIdx.x * 16;

  for (int i = tid; i < 2 * 16 * 128; i += 512) {
    (&h1s[0][0])[i] = 0; (&h2s[0][0])[i] = 0;
  }
  if (tid < 256) {  // zero the k>=16 pad of both x buffers
    const int s = tid >> 4, d = tid & 15;
    xb[0][s * 32 + 16 + d] = 0; xb[1][s * 32 + 16 + d] = 0;
    xb[0][s * 32 + d] = bf16u(x[((size_t)(seqbase + s) * T_ + 0) * 16 + d]);
  }
  {
    const uint4* src = reinterpret_cast<const uint4*>(whh1f);
    uint4* dst = reinterpret_cast<uint4*>(w1l);
    for (int i = tid; i < 8192; i += 512) dst[i] = src[i];
  }

  s8v whh0[4][4], wih1[4][4], wx0[4];
  float b0[4], b1[4];
  int wb[4];
#pragma unroll
  for (int g = 0; g < 4; ++g) {
    const int gr = g * 128 + 16 * wv + l16;   // W row = gate col
    b0[g] = bih0[gr] + bhh0[gr];
    b1[g] = bih1[gr] + bhh1[gr];
    wb[g] = ((g * 8 + wv) * 4) * 1024 + lane * 16;
#pragma unroll
    for (int kt = 0; kt < 4; ++kt) {
      const int k0 = kt * 32 + lq * 8;
      whh0[g][kt] = load8(Whh0 + (size_t)gr * 128 + k0);
      wih1[g][kt] = load8(Wih1 + (size_t)gr * 128 + k0);
    }
    if (lq < 2) wx0[g] = load8(Wih0 + (size_t)gr * 16 + lq * 8);
    else { s8v z; for (int i2 = 0; i2 < 8; ++i2) z[i2] = 0; wx0[g] = z; }
  }

  float c1[4] = {0.f, 0.f, 0.f, 0.f}, c2[4] = {0.f, 0.f, 0.f, 0.f};
  int cur = 0;
  __syncthreads();

  const int sw = (l16 & 7) << 4;
  const int hunit = 16 * wv + l16;

  for (int t = 0; t < T_; ++t) {
    const int xc = t & 1;
    float xv = 0.f;
    const bool xpf = (t + 1 < T_) && (tid < 256);
    if (xpf) {
      const int s = tid >> 4, d = tid & 15;
      xv = x[((size_t)(seqbase + s) * T_ + (t + 1)) * 16 + d];
    }

    // ================= layer-0 MFMA =================
    f4v acc[4];
#pragma unroll
    for (int g = 0; g < 4; ++g) acc[g] = f4v{b0[g], b0[g], b0[g], b0[g]};
    {
      const s8v ax = *reinterpret_cast<const s8v*>(
          reinterpret_cast<const char*>(&xb[xc][0]) + l16 * 64 + lq * 16);
#pragma unroll
      for (int g = 0; g < 4; ++g) acc[g] = mfma16(ax, wx0[g], acc[g]);
    }
#pragma unroll
    for (int kt = 0; kt < 4; ++kt) {
      const s8v ah = *reinterpret_cast<const s8v*>(
          reinterpret_cast<const char*>(&h1s[cur][0]) + l16 * 256 +
          ((kt * 64 + lq * 16) ^ sw));
#pragma unroll
      for (int g = 0; g < 4; ++g) acc[g] = mfma16(ah, whh0[g][kt], acc[g]);
    }
#pragma unroll
    for (int ss = 0; ss < 4; ++ss) {
      const int seq = lq * 4 + ss;
      const float iv = sig_(acc[0][ss]);
      const float fv = sig_(acc[1][ss]);
      const float gv = tanh_(acc[2][ss]);
      const float ov = sig_(acc[3][ss]);
      c1[ss] = fv * c1[ss] + iv * gv;
      const float hv = ov * tanh_(c1[ss]);
      *reinterpret_cast<unsigned short*>(
          reinterpret_cast<char*>(&h1s[cur ^ 1][0]) + seq * 256 +
          ((2 * hunit) ^ ((seq & 7) << 4))) = bf16u(hv);
    }
    barrier_lds();

    // ================= layer-1 MFMA =================
#pragma unroll
    for (int g = 0; g < 4; ++g) acc[g] = f4v{b1[g], b1[g], b1[g], b1[g]};
#pragma unroll
    for (int kt = 0; kt < 4; ++kt) {
      const int ko = (kt * 64 + lq * 16) ^ sw;
      const s8v a1 = *reinterpret_cast<const s8v*>(
          reinterpret_cast<const char*>(&h1s[cur ^ 1][0]) + l16 * 256 + ko);
      const s8v a2 = *reinterpret_cast<const s8v*>(
          reinterpret_cast<const char*>(&h2s[cur][0]) + l16 * 256 + ko);
#pragma unroll
      for (int g = 0; g < 4; ++g) {
        acc[g] = mfma16(a1, wih1[g][kt], acc[g]);
        const s8v bw = *reinterpret_cast<const s8v*>(
            reinterpret_cast<const char*>(w1l) + wb[g] + kt * 1024);
        acc[g] = mfma16(a2, bw, acc[g]);
      }
    }
#pragma unroll
    for (int ss = 0; ss < 4; ++ss) {
      const int seq = lq * 4 + ss;
      const float iv = sig_(acc[0][ss]);
      const float fv = sig_(acc[1][ss]);
      const float gv = tanh_(acc[2][ss]);
      const float ov = sig_(acc[3][ss]);
      c2[ss] = fv * c2[ss] + iv * gv;
      const float hv = ov * tanh_(c2[ss]);
      *reinterpret_cast<unsigned short*>(
          reinterpret_cast<char*>(&h2s[cur ^ 1][0]) + seq * 256 +
          ((2 * hunit) ^ ((seq & 7) << 4))) = bf16u(hv);
    }
    if (xpf) {
      const int s = tid >> 4, d = tid & 15;
      xb[xc ^ 1][s * 32 + d] = bf16u(xv);
    }
    barrier_lds();

    {
      const int seq = tid >> 5;
      const int u0  = (tid & 31) * 4;
      const uint2 v = *reinterpret_cast<const uint2*>(
          reinterpret_cast<const char*>(&h2s[cur ^ 1][0]) + seq * 256 +
          ((2 * u0) ^ ((seq & 7) << 4)));
      *reinterpret_cast<uint2*>(
          hist + ((size_t)(seqbase + seq) * T_ + t) * H_ + u0) = v;
    }
    cur ^= 1;
  }
}

// ---------------------------------------------------------------------------
// K2 (round-13): pooling + LN1 + FUSED k3 (proj + qkv). rep never leaves
// LDS; writes q/k/v directly. projW/Wq/Wk/Wv are L2-resident (96KB total).
// ---------------------------------------------------------------------------
__global__ __launch_bounds__(384, 2) void k2_pool_mfma(
    const unsigned short* __restrict__ hist,
    const unsigned short* __restrict__ w1f,
    const float* __restrict__ attn_w,
    const float* __restrict__ W2,
    const float* __restrict__ ln1g, const float* __restrict__ ln1b,
    const float* __restrict__ projW, const float* __restrict__ projb,
    const float* __restrict__ Wq, const float* __restrict__ bq,
    const float* __restrict__ Wk, const float* __restrict__ bk,
    const float* __restrict__ Wv, const float* __restrict__ bv,
    float* __restrict__ qb_, float* __restrict__ kb_, float* __restrict__ vb_)
{
  __shared__ __align__(16) unsigned short hst[96 * 128];
  __shared__ float sS[128], aws[128], alpha[96], wts[96], red[128], hTs[128];
  __shared__ float ctxP[3][128];
  __shared__ float xps[64];

  const int n = blockIdx.x;
  const int tid = threadIdx.x;
  const int lane = tid & 63;
  const int wv = tid >> 6;
  const int l16 = lane & 15;
  const int lq = lane >> 4;

  const unsigned short* hsrc = hist + (size_t)n * T_ * H_;
  for (int i = tid; i < 1536; i += 384) {
    const int row = i >> 4, c16 = i & 15;
    const uint4 v = *reinterpret_cast<const uint4*>(hsrc + row * 128 + c16 * 8);
    *reinterpret_cast<uint4*>(
        reinterpret_cast<char*>(hst) + row * 256 + ((c16 * 16) ^ ((row & 7) << 4))) = v;
  }
  if (tid < 128) aws[tid] = attn_w[tid];
  __syncthreads();

  if (tid < 128) hTs[tid] = bf2f(hst[95 * 128 + (tid ^ 56)]);
  __syncthreads();
  if (tid < 128) {
    float s = 0.f;
    for (int h = 0; h < 128; ++h) s += hTs[h] * W2[(size_t)h * 128 + tid];
    sS[tid] = s;
  }
  __syncthreads();

  {
    const int row0 = wv * 16 + l16;
    f4v acc[8];
#pragma unroll
    for (int nt = 0; nt < 8; ++nt) acc[nt] = f4v{0.f, 0.f, 0.f, 0.f};
#pragma unroll
    for (int kt = 0; kt < 4; ++kt) {
      const s8v a = *reinterpret_cast<const s8v*>(
          reinterpret_cast<const char*>(hst) + row0 * 256 +
          ((kt * 64 + lq * 16) ^ ((row0 & 7) << 4)));
#pragma unroll
      for (int nt = 0; nt < 8; ++nt) {
        const s8v b = *reinterpret_cast<const s8v*>(
            w1f + ((((nt << 2) + kt) << 2 | lq) * 16 + l16) * 8);
        acc[nt] = mfma16(a, b, acc[nt]);
      }
    }
    float pa[4] = {0.f, 0.f, 0.f, 0.f};
#pragma unroll
    for (int nt = 0; nt < 8; ++nt) {
      const int col = nt * 16 + l16;
      const float ss = sS[col], aw = aws[col];
#pragma unroll
      for (int i2 = 0; i2 < 4; ++i2) pa[i2] += tanh_(acc[nt][i2] + ss) * aw;
    }
#pragma unroll
    for (int i2 = 0; i2 < 4; ++i2) {
      float v = pa[i2];
      v += __shfl_xor(v, 8); v += __shfl_xor(v, 4);
      v += __shfl_xor(v, 2); v += __shfl_xor(v, 1);
      if (l16 == 0) alpha[wv * 16 + lq * 4 + i2] = v;
    }
  }
  __syncthreads();

  if (tid < 128) red[tid] = (tid < 96) ? alpha[tid] : -1e30f;
  __syncthreads();
  for (int sft = 64; sft > 0; sft >>= 1) {
    if (tid < sft) red[tid] = fmaxf(red[tid], red[tid + sft]);
    __syncthreads();
  }
  const float mx = red[0];
  __syncthreads();
  if (tid < 128) {
    const float e = (tid < 96) ? __expf(alpha[tid] - mx) : 0.f;
    red[tid] = e;
    if (tid < 96) wts[tid] = e;
  }
  __syncthreads();
  for (int sft = 64; sft > 0; sft >>= 1) {
    if (tid < sft) red[tid] += red[tid + sft];
    __syncthreads();
  }
  const float inv = rcp_(red[0]);
  if (tid < 96) wts[tid] *= inv;
  __syncthreads();

  {
    const int th = tid >> 7, j = tid & 127;
    float cp = 0.f;
    for (int t = th * 32; t < th * 32 + 32; ++t)
      cp += wts[t] * bf2f(hst[t * 128 + (j ^ ((t & 7) << 3))]);
    ctxP[th][j] = cp;
  }
  __syncthreads();
  if (tid < 128) {
    hTs[tid] = ctxP[0][tid] + ctxP[1][tid] + ctxP[2][tid];
    red[tid] = hTs[tid];
  }
  __syncthreads();
  for (int sft = 64; sft > 0; sft >>= 1) {
    if (tid < sft) red[tid] += red[tid + sft];
    __syncthreads();
  }
  const float mean = red[0] * (1.f / 128.f);
  __syncthreads();
  if (tid < 128) { const float d = hTs[tid] - mean; red[tid] = d * d; }
  __syncthreads();
  for (int sft = 64; sft > 0; sft >>= 1) {
    if (tid < sft) red[tid] += red[tid + sft];
    __syncthreads();
  }
  const float var = red[0] * (1.f / 128.f);
  __syncthreads();
  // rep stays in LDS (hTs), then fused proj + qkv
  if (tid < 128)
    hTs[tid] = (hTs[tid] - mean) * rsqrtf(var + 1e-5f) * ln1g[tid] + ln1b[tid];
  __syncthreads();
  if (tid < 64) {
    float xpv = projb[tid];
    for (int kk = 0; kk < 128; ++kk) xpv += hTs[kk] * projW[kk * 64 + tid];
    xps[tid] = xpv;
  }
  __syncthreads();
  if (tid < 192) {
    const int which = tid >> 6, col = tid & 63;
    const float* W = (which == 0) ? Wq : (which == 1) ? Wk : Wv;
    const float* bb = (which == 0) ? bq : (which == 1) ? bk : bv;
    float acc = bb[col];
    for (int kk = 0; kk < 64; ++kk) acc += xps[kk] * W[kk * 64 + col];
    float* dst = (which == 0) ? qb_ : (which == 1) ? kb_ : vb_;
    dst[(size_t)n * 64 + col] = acc;
  }
}

// ---------------------------------------------------------------------------
// K4: batched attention (round-12 kernel, verified).
// ---------------------------------------------------------------------------
__global__ __launch_bounds__(512) void k4_attn_b(
    const float* __restrict__ q, const float* __restrict__ kbuf,
    const float* __restrict__ vbuf,
    const int* __restrict__ ranks, const float* __restrict__ glut,
    float* __restrict__ ao)
{
  __shared__ float Ks[128][65], Vs[128][65];
  __shared__ float qs[16][64];
  __shared__ float wrow[8][128];
  __shared__ float gl[51];
  __shared__ int rs[128];

  const int tid = threadIdx.x, lane = tid & 63, wv = tid >> 6;
  const int b = blockIdx.x >> 3;
  const int rowbase = (blockIdx.x & 7) * 16;

  for (int i = tid; i < 8192; i += 512) {
    Ks[i >> 6][i & 63] = kbuf[(size_t)b * 8192 + i];
    Vs[i >> 6][i & 63] = vbuf[(size_t)b * 8192 + i];
  }
  for (int i = tid; i < 1024; i += 512)
    qs[i >> 6][i & 63] = q[((size_t)b * 128 + rowbase) * 64 + i];
  if (tid < 128) rs[tid] = ranks[b * 128 + tid];
  if (tid >= 128 && tid < 179) gl[tid - 128] = glut[tid - 128];
  __syncthreads();

  const int m0 = lane, m1 = lane + 64;
#pragma unroll
  for (int rr = 0; rr < 2; ++rr) {
    const int lr = wv * 2 + rr;
    const int rn = rs[rowbase + lr];
    float s0 = 0.f, s1 = 0.f;
#pragma unroll 8
    for (int d = 0; d < 64; ++d) {
      const float qd = qs[lr][d];
      s0 += qd * Ks[m0][d];
      s1 += qd * Ks[m1][d];
    }
    int d0 = rn - rs[m0]; if (d0 < 0) d0 = -d0; if (d0 > 50) d0 = 50;
    int d1 = rn - rs[m1]; if (d1 < 0) d1 = -d1; if (d1 > 50) d1 = 50;
    s0 *= 0.125f * gl[d0];
    s1 *= 0.125f * gl[d1];
    float mx = fmaxf(s0, s1);
#pragma unroll
    for (int off = 32; off; off >>= 1) mx = fmaxf(mx, __shfl_xor(mx, off));
    const float e0 = __expf(s0 - mx), e1 = __expf(s1 - mx);
    float sum = e0 + e1;
#pragma unroll
    for (int off = 32; off; off >>= 1) sum += __shfl_xor(sum, off);
    const float inv = rcp_(sum);
    wrow[wv][m0] = e0 * inv;
    wrow[wv][m1] = e1 * inv;
    asm volatile("s_waitcnt lgkmcnt(0)" ::: "memory");
    float acc = 0.f;
#pragma unroll 4
    for (int m = 0; m < 128; ++m) acc += wrow[wv][m] * Vs[m][lane];
    ao[((size_t)b * 128 + rowbase + lr) * 64 + lane] = acc;
  }
}

// ---------------------------------------------------------------------------
// K5 (round-13): wave-per-row FF head. Block = 512 thr handles 8 rows;
// all weights staged once in LDS (~80KB, 2 blocks/CU); hid via shfl
// broadcast + stride-1 LDS reads; LN via xor-shuffles; 3 block barriers
// total (vs ~14 in the old 128-thread-per-row version).
// ---------------------------------------------------------------------------
__global__ __launch_bounds__(512) void k5_ffout_w(
    const float* __restrict__ ao,
    const float* __restrict__ ff1W, const float* __restrict__ ff1b,
    const float* __restrict__ ff2W, const float* __restrict__ ff2b,
    const float* __restrict__ ln2g, const float* __restrict__ ln2b,
    const float* __restrict__ sp1W, const float* __restrict__ sp1b,
    const float* __restrict__ sp2W, const float* __restrict__ sp2b,
    float* __restrict__ out)
{
  __shared__ float f1[64][128];    // ff1W, 32KB
  __shared__ float f2[128][64];    // ff2W, 32KB
  __shared__ float s1[64][32];     // sp1W, 8KB
  __shared__ float f1b[128], f2b[64], g2[64], b2[64], s1b[32], s2w[32];
  __shared__ float hbuf[8][128], fbuf[8][64];

  const int tid = threadIdx.x, lane = tid & 63, wv = tid >> 6;
  for (int i = tid; i < 8192; i += 512) f1[i >> 7][i & 127] = ff1W[i];
  for (int i = tid; i < 8192; i += 512) f2[i >> 6][i & 63] = ff2W[i];
  for (int i = tid; i < 2048; i += 512) s1[i >> 5][i & 31] = sp1W[i];
  if (tid < 128) f1b[tid] = ff1b[tid];
  else if (tid < 192) f2b[tid - 128] = ff2b[tid - 128];
  else if (tid < 256) g2[tid - 192] = ln2g[tid - 192];
  else if (tid < 320) b2[tid - 256] = ln2b[tid - 256];
  else if (tid < 352) s1b[tid - 320] = sp1b[tid - 320];
  else if (tid < 384) s2w[tid - 352] = sp2W[tid - 352];
  __syncthreads();

  const int row = blockIdx.x * 8 + wv;
  const float a = ao[(size_t)row * 64 + lane];
  float h0 = f1b[lane], h1 = f1b[lane + 64];
#pragma unroll 8
  for (int d = 0; d < 64; ++d) {
    const float ad = __shfl(a, d);
    h0 += ad * f1[d][lane];
    h1 += ad * f1[d][lane + 64];
  }
  hbuf[wv][lane] = fmaxf(h0, 0.f);
  hbuf[wv][lane + 64] = fmaxf(h1, 0.f);
  __syncthreads();

  float yv = f2b[lane];
#pragma unroll 8
  for (int j = 0; j < 128; ++j) yv += hbuf[wv][j] * f2[j][lane];
  // LN over the wave's 64 lanes
  float s = yv;
#pragma unroll
  for (int off = 32; off; off >>= 1) s += __shfl_xor(s, off);
  const float mean = s * (1.f / 64.f);
  float d2 = (yv - mean) * (yv - mean);
#pragma unroll
  for (int off = 32; off; off >>= 1) d2 += __shfl_xor(d2, off);
  const float var = d2 * (1.f / 64.f);
  fbuf[wv][lane] = (yv - mean) * rsqrtf(var + 1e-5f) * g2[lane] + b2[lane];
  __syncthreads();

  float val = 0.f;
  if (lane < 32) {
    float h2v = s1b[lane];
#pragma unroll 8
    for (int c = 0; c < 64; ++c) h2v += fbuf[wv][c] * s1[c][lane];
    val = fmaxf(h2v, 0.f) * s2w[lane];
  }
#pragma unroll
  for (int off = 16; off; off >>= 1) val += __shfl_xor(val, off);
  if (lane == 0) out[row] = sig_(val + sp2b[0]);
}

}  // namespace

extern "C" void kernel_launch(void* const* d_in, const int* in_sizes, int n_in,
                              void* d_out, int out_size, void* d_ws, size_t ws_size,
                              hipStream_t stream)
{
  const float* x      = (const float*)d_in[0];
  const int*   ranks  = (const int*)  d_in[1];
  const float* Wih0   = (const float*)d_in[2];
  const float* Whh0   = (const float*)d_in[3];
  const float* bih0   = (const float*)d_in[4];
  const float* bhh0   = (const float*)d_in[5];
  const float* Wih1   = (const float*)d_in[6];
  const float* Whh1   = (const float*)d_in[7];
  const float* bih1   = (const float*)d_in[8];
  const float* bhh1   = (const float*)d_in[9];
  const float* attn_w = (const float*)d_in[10];
  const float* W1     = (const float*)d_in[11];
  const float* W2     = (const float*)d_in[12];
  const float* ln1g   = (const float*)d_in[13];
  const float* ln1b   = (const float*)d_in[14];
  const float* projW  = (const float*)d_in[15];
  const float* projb  = (const float*)d_in[16];
  const float* Wq     = (const float*)d_in[17];
  const float* bq     = (const float*)d_in[18];
  const float* Wk     = (const float*)d_in[19];
  const float* bk     = (const float*)d_in[20];
  const float* Wv     = (const float*)d_in[21];
  const float* bv     = (const float*)d_in[22];
  const float* remb   = (const float*)d_in[23];
  const float* rw1W   = (const float*)d_in[24];
  const float* rw1b   = (const float*)d_in[25];
  const float* rw2W   = (const float*)d_in[26];
  const float* ff1W   = (const float*)d_in[27];
  const float* ff1b   = (const float*)d_in[28];
  const float* ff2W   = (const float*)d_in[29];
  const float* ff2b   = (const float*)d_in[30];
  const float* ln2g   = (const float*)d_in[31];
  const float* ln2b   = (const float*)d_in[32];
  const float* sp1W   = (const float*)d_in[33];
  const float* sp1b   = (const float*)d_in[34];
  const float* sp2W   = (const float*)d_in[35];
  const float* sp2b   = (const float*)d_in[36];
  float* out = (float*)d_out;

  char* ws = (char*)d_ws;
  unsigned short* hist = (unsigned short*)ws;            // 4096*96*128 bf16 = 96 MB
  size_t off = (size_t)4096 * 96 * 128 * 2;
  float* rep = (float*)(ws + off); off += (size_t)4096 * 128 * 4;  // unused (kept layout)
  float* qb  = (float*)(ws + off); off += (size_t)4096 * 64 * 4;
  float* kb  = (float*)(ws + off); off += (size_t)4096 * 64 * 4;
  float* vb  = (float*)(ws + off); off += (size_t)4096 * 64 * 4;
  float* aob = (float*)(ws + off); off += (size_t)4096 * 64 * 4;
  unsigned short* w1f   = (unsigned short*)(ws + off); off += 16384 * 2;
  float* glut = (float*)(ws + off); off += 64 * 4;
  unsigned short* whh1f = (unsigned short*)(ws + off); off += 65536 * 2;
  (void)rep;

  k0_gate<<<dim3(1), dim3(64), 0, stream>>>(remb, rw1W, rw1b, rw2W, glut);
  k0_w1<<<dim3(64), dim3(256), 0, stream>>>(W1, w1f);
  k0_whh1<<<dim3(256), dim3(256), 0, stream>>>(Whh1, whh1f);
  k1_lstm_mfma<<<dim3(256), dim3(512), 0, stream>>>(
      x, Wih0, Whh0, bih0, bhh0, Wih1, (const float*)whh1f, bih1, bhh1, hist);
  k2_pool_mfma<<<dim3(4096), dim3(384), 0, stream>>>(
      hist, w1f, attn_w, W2, ln1g, ln1b,
      projW, projb, Wq, bq, Wk, bk, Wv, bv, qb, kb, vb);
  k4_attn_b<<<dim3(256), dim3(512), 0, stream>>>(
      qb, kb, vb, ranks, glut, aob);
  k5_ffout_w<<<dim3(512), dim3(512), 0, stream>>>(
      aob, ff1W, ff1b, ff2W, ff2b, ln2g, ln2b, sp1W, sp1b, sp2W, sp2b, out);
}